// Round 4
// baseline (394.747 us; speedup 1.0000x reference)
//
#include <hip/hip_runtime.h>
#include <hip/hip_bf16.h>

// EPMoE: E=8, K=2, D=1024, F=2048, T=2048, ROWS=4096.
// R4: convT ELIMINATED. Three structurally different convT variants (R0/R1/R3)
// all pinned at ~86us / 3.3 TB/s effective with no saturated counter (HBM 29%,
// VALU 7%, LDS trivial) and FETCH unchanged by NT stores -> stop micro-tuning,
// remove the pass. gemm1/gemm2 now stage B directly from fp32 weights
// (read fp32 tile -> pack_rn k-pairs -> ds_write into the SAME XOR-swizzled
// LDS layout the MFMA loop already reads; compute loop untouched).
// Working set drops to 192MB weights + 40MB ws ~= L3 capacity, so fp32 B
// reads (5x m-tile reuse per expert) are largely L2/L3 hits.
// R3 lessons: NT stores did NOT reduce FETCH (theory dead); tile_remap+NT
// regressed total 320->333 -> both reverted.
// A-side staging: global_load_lds + XOR swizzle ([R][64] bf16 rows = 128B =
// 32 banks; physical 16B chunk j of row m holds logical chunk j^(m&7),
// applied on global source address; lds dst stays lane-contiguous).
// gemm1/2 accumulators: 64/32 AGPR; launch_bounds (256,3) both (prior lesson:
// 128 AGPR + 120 VGPR at w=3 spilled -> keep acc small, cap waves at 3).

#define D_DIM 1024
#define F_DIM 2048
#define ROWS 4096
#define MAXTILE 40
#define LDK 72   // fallback-path LDS k-stride

using f32x4 = __attribute__((ext_vector_type(4))) float;
using s16x8 = __attribute__((ext_vector_type(8))) short;

__device__ __forceinline__ unsigned pack_trunc(float lo, float hi) {
  return (__float_as_uint(lo) >> 16) | (__float_as_uint(hi) & 0xffff0000u);
}
__device__ __forceinline__ unsigned short bf_rn(float f) {
  unsigned u = __float_as_uint(f);
  u += 0x7fffu + ((u >> 16) & 1u);
  return (unsigned short)(u >> 16);
}
__device__ __forceinline__ unsigned pack_rn(float lo, float hi) {
  return (unsigned)bf_rn(lo) | ((unsigned)bf_rn(hi) << 16);
}

typedef const __attribute__((address_space(1))) void* gp_t;
typedef __attribute__((address_space(3))) void* lp_t;
__device__ __forceinline__ void load16(const void* g, void* l) {
  __builtin_amdgcn_global_load_lds((gp_t)g, (lp_t)l, 16, 0, 0);
}

// -------- routing: stable counting sort by expert (ids staged in LDS) --------
__global__ __launch_bounds__(512) void route_kernel(const int* __restrict__ ids,
                                                    int* __restrict__ sorted_flat,
                                                    int* __restrict__ unsort,
                                                    int* __restrict__ tile_meta) {
  __shared__ int sid[ROWS];
  __shared__ int cnt[8];
  __shared__ int off[9];
  const int tid = threadIdx.x;
#pragma unroll
  for (int j = 0; j < 2; j++) {
    int idx = tid + j * 512;                    // int4 index
    *(int4*)&sid[idx * 4] = *(const int4*)&ids[idx * 4];
  }
  __syncthreads();
  const int w = tid >> 6, lane = tid & 63;
  int c = 0;
  for (int base = 0; base < ROWS; base += 64)
    c += __popcll(__ballot(sid[base + lane] == w));
  if (lane == 0) cnt[w] = c;
  __syncthreads();
  if (tid == 0) {
    int o = 0;
    for (int e = 0; e < 8; e++) { off[e] = o; o += cnt[e]; }
    off[8] = o;
    int nT = 0;
    for (int e = 0; e < 8; e++) {
      for (int r0 = off[e]; r0 < off[e + 1]; r0 += 128) {
        tile_meta[1 + 3 * nT] = r0;
        tile_meta[2 + 3 * nT] = off[e + 1];
        tile_meta[3 + 3 * nT] = e;
        nT++;
      }
    }
    tile_meta[0] = nT;
  }
  __syncthreads();
  int pos = off[w];
  const unsigned long long below = (1ull << lane) - 1ull;
  for (int base = 0; base < ROWS; base += 64) {
    unsigned long long m = __ballot(sid[base + lane] == w);
    if (sid[base + lane] == w) {
      int p = pos + __popcll(m & below);
      sorted_flat[p] = base + lane;
      unsort[base + lane] = p;
    }
    pos += __popcll(m);
  }
}

__global__ void zero_kernel(float4* __restrict__ p, int n4) {
  int i = blockIdx.x * blockDim.x + threadIdx.x;
  if (i < n4) p[i] = float4{0.f, 0.f, 0.f, 0.f};
}

// ---------------- gather: x fp32 -> x_sorted bf16 ----------------
__global__ __launch_bounds__(256) void gather_kernel(const float* __restrict__ x,
                                                     const int* __restrict__ sorted_flat,
                                                     unsigned short* __restrict__ xs) {
  const int r = blockIdx.x;
  const int tok = sorted_flat[r] >> 1;
  const float4 v = *(const float4*)(x + (size_t)tok * D_DIM + threadIdx.x * 4);
  *(uint2*)(xs + (size_t)r * D_DIM + threadIdx.x * 4) =
      make_uint2(pack_rn(v.x, v.y), pack_rn(v.z, v.w));
}

// swizzled frag address: physical chunk = logical_chunk ^ (row&7)
__device__ __forceinline__ int sw(int row, int chunk) {
  return row * 64 + ((chunk ^ (row & 7)) << 3);
}

// --- fused B-staging: fp32 W tile [64k x 64n] (row stride ldw) -> swizzled
// bf16 LDS [n][k] (uint view, 32 uints/row; chunk ch of row n at phys
// (ch^(n&7))*4). Thread (kp = tid&15, nq = tid>>4); it covers kpairs kp,kp+16.
// Reads: 2 float4 per it (rows 2kpp, 2kpp+1); 16 lanes/row-pair = 256B.
// Writes: 4x b32 per it (same kpair, n = nq*4..+3), bounded ~2-4-way banks.
__device__ __forceinline__ void stage_bfp32(const float* __restrict__ Wt, int ldw,
                                            unsigned* __restrict__ Bu,
                                            int kp, int nq) {
#pragma unroll
  for (int it = 0; it < 2; it++) {
    const int kpp = kp + it * 16;           // kpair 0..31
    const float* p = Wt + (size_t)(2 * kpp) * ldw + nq * 4;
    const float4 va = *(const float4*)p;
    const float4 vb = *(const float4*)(p + ldw);
    const int ch = kpp >> 2, ql = kpp & 3;  // 16B chunk, uint-in-chunk
    const int nb = nq * 4;
    Bu[(nb + 0) * 32 + ((ch ^ ((nb + 0) & 7)) << 2) + ql] = pack_rn(va.x, vb.x);
    Bu[(nb + 1) * 32 + ((ch ^ ((nb + 1) & 7)) << 2) + ql] = pack_rn(va.y, vb.y);
    Bu[(nb + 2) * 32 + ((ch ^ ((nb + 2) & 7)) << 2) + ql] = pack_rn(va.z, vb.z);
    Bu[(nb + 3) * 32 + ((ch ^ ((nb + 3) & 7)) << 2) + ql] = pack_rn(va.w, vb.w);
  }
}

// ------- GEMM1: xs @ (wi0,wi1 fp32, packed inline) -> h = silu(g0)*g1 -------
// 128(m) x 64(n) tiles.
__global__ __launch_bounds__(256, 3) void gemm1_kernel(
    const unsigned short* __restrict__ xs, const float* __restrict__ wi0,
    const float* __restrict__ wi1, const int* __restrict__ tile_meta,
    unsigned short* __restrict__ h) {
  __shared__ unsigned short As[128 * 64];
  __shared__ unsigned short B0s[64 * 64];
  __shared__ unsigned short B1s[64 * 64];
  const int tile = blockIdx.x;
  if (tile >= tile_meta[0]) return;
  const int row0 = tile_meta[1 + 3 * tile];
  const int rowEnd = tile_meta[2 + 3 * tile];
  const int e = tile_meta[3 + 3 * tile];
  const int n0 = blockIdx.y * 64;
  const float* W0 = wi0 + (size_t)e * D_DIM * F_DIM + n0;  // [k][n], ld=F
  const float* W1 = wi1 + (size_t)e * D_DIM * F_DIM + n0;

  const int tid = threadIdx.x;
  const int lane = tid & 63, wv = tid >> 6;
  const int wm = (wv & 1) * 64, wn = (wv >> 1) * 32;
  const int lm = lane & 15, lq = lane >> 4;
  const int srow = lane >> 3;                       // staging row-in-chunk
  const int skk = ((lane & 7) ^ srow) << 3;         // swizzled source elem off
  const int kp = tid & 15, nq = tid >> 4;           // B-staging coords

  f32x4 acc0[4][2], acc1[4][2];
#pragma unroll
  for (int i = 0; i < 4; i++)
#pragma unroll
    for (int j = 0; j < 2; j++) { acc0[i][j] = 0.f; acc1[i][j] = 0.f; }

  for (int k0 = 0; k0 < D_DIM; k0 += 64) {
    __syncthreads();
#pragma unroll
    for (int r = 0; r < 4; r++) {                 // A: 16 chunks, 4/wave
      const int c = r * 4 + wv;
      const int m = c * 8 + srow;
      int mc = row0 + m; if (mc > ROWS - 1) mc = ROWS - 1;
      load16(xs + (size_t)mc * D_DIM + k0 + skk, (char*)As + c * 1024);
    }
    stage_bfp32(W0 + (size_t)k0 * F_DIM, F_DIM, (unsigned*)B0s, kp, nq);
    stage_bfp32(W1 + (size_t)k0 * F_DIM, F_DIM, (unsigned*)B1s, kp, nq);
    __syncthreads();
#pragma unroll
    for (int ks = 0; ks < 64; ks += 32) {
      const int cb = (ks >> 3) + lq;
      s16x8 af[4], b0[2], b1[2];
#pragma unroll
      for (int t = 0; t < 4; t++)
        af[t] = *(const s16x8*)&As[sw(wm + t * 16 + lm, cb)];
#pragma unroll
      for (int t = 0; t < 2; t++) {
        b0[t] = *(const s16x8*)&B0s[sw(wn + t * 16 + lm, cb)];
        b1[t] = *(const s16x8*)&B1s[sw(wn + t * 16 + lm, cb)];
      }
#pragma unroll
      for (int im = 0; im < 4; im++)
#pragma unroll
        for (int in = 0; in < 2; in++) {
          acc0[im][in] = __builtin_amdgcn_mfma_f32_16x16x32_bf16(
              af[im], b0[in], acc0[im][in], 0, 0, 0);
          acc1[im][in] = __builtin_amdgcn_mfma_f32_16x16x32_bf16(
              af[im], b1[in], acc1[im][in], 0, 0, 0);
        }
    }
  }
#pragma unroll
  for (int im = 0; im < 4; im++) {
    int gmB = row0 + wm + im * 16 + lq * 4;
#pragma unroll
    for (int in = 0; in < 2; in++) {
      int gn = n0 + wn + in * 16 + lm;
#pragma unroll
      for (int r = 0; r < 4; r++) {
        int gm = gmB + r;
        if (gm < rowEnd) {
          float g = acc0[im][in][r];
          float s = g / (1.f + __expf(-g));
          h[(size_t)gm * F_DIM + gn] = bf_rn(s * acc1[im][in][r]);
        }
      }
    }
  }
}

// -------- GEMM2: h @ wo (fp32, packed inline) -> y (128x64 tiles) --------
__global__ __launch_bounds__(256, 3) void gemm2_kernel(
    const unsigned short* __restrict__ h, const float* __restrict__ wo,
    const int* __restrict__ tile_meta, float* __restrict__ y) {
  __shared__ unsigned short As[128 * 64];
  __shared__ unsigned short Bs[64 * 64];
  const int tile = blockIdx.x;
  if (tile >= tile_meta[0]) return;
  const int row0 = tile_meta[1 + 3 * tile];
  const int rowEnd = tile_meta[2 + 3 * tile];
  const int e = tile_meta[3 + 3 * tile];
  const int n0 = blockIdx.y * 64;
  const float* W = wo + (size_t)e * F_DIM * D_DIM + n0;   // [k=f][n=d], ld=D

  const int tid = threadIdx.x;
  const int lane = tid & 63, wv = tid >> 6;
  const int wm = (wv & 1) * 64, wn = (wv >> 1) * 32;
  const int lm = lane & 15, lq = lane >> 4;
  const int srow = lane >> 3;
  const int skk = ((lane & 7) ^ srow) << 3;
  const int kp = tid & 15, nq = tid >> 4;

  f32x4 acc[4][2];
#pragma unroll
  for (int i = 0; i < 4; i++)
#pragma unroll
    for (int j = 0; j < 2; j++) acc[i][j] = 0.f;

  for (int k0 = 0; k0 < F_DIM; k0 += 64) {
    __syncthreads();
#pragma unroll
    for (int r = 0; r < 4; r++) {
      const int c = r * 4 + wv;
      const int m = c * 8 + srow;
      int mc = row0 + m; if (mc > ROWS - 1) mc = ROWS - 1;
      load16(h + (size_t)mc * F_DIM + k0 + skk, (char*)As + c * 1024);
    }
    stage_bfp32(W + (size_t)k0 * D_DIM, D_DIM, (unsigned*)Bs, kp, nq);
    __syncthreads();
#pragma unroll
    for (int ks = 0; ks < 64; ks += 32) {
      const int cb = (ks >> 3) + lq;
      s16x8 af[4], bf[2];
#pragma unroll
      for (int t = 0; t < 4; t++)
        af[t] = *(const s16x8*)&As[sw(wm + t * 16 + lm, cb)];
#pragma unroll
      for (int t = 0; t < 2; t++)
        bf[t] = *(const s16x8*)&Bs[sw(wn + t * 16 + lm, cb)];
#pragma unroll
      for (int im = 0; im < 4; im++)
#pragma unroll
        for (int in = 0; in < 2; in++)
          acc[im][in] = __builtin_amdgcn_mfma_f32_16x16x32_bf16(
              af[im], bf[in], acc[im][in], 0, 0, 0);
    }
  }
#pragma unroll
  for (int im = 0; im < 4; im++) {
    int gmB = row0 + wm + im * 16 + lq * 4;
#pragma unroll
    for (int in = 0; in < 2; in++) {
      int gn = n0 + wn + in * 16 + lm;
#pragma unroll
      for (int r = 0; r < 4; r++) {
        int gm = gmB + r;
        if (gm < rowEnd) y[(size_t)gm * D_DIM + gn] = acc[im][in][r];
      }
    }
  }
}

// ---------------- combine: out[t] = tw0*y[unsort[2t]] + tw1*y[unsort[2t+1]] ----
__global__ __launch_bounds__(256) void combine_kernel(const float* __restrict__ y,
                                                      const float* __restrict__ tw,
                                                      const int* __restrict__ unsort,
                                                      float* __restrict__ out) {
  const int tkn = blockIdx.x;
  const int r0 = unsort[2 * tkn], r1 = unsort[2 * tkn + 1];
  const float w0 = tw[2 * tkn], w1 = tw[2 * tkn + 1];
  const int c = threadIdx.x * 4;
  float4 a = *(const float4*)(y + (size_t)r0 * D_DIM + c);
  float4 b = *(const float4*)(y + (size_t)r1 * D_DIM + c);
  float4 o = {w0 * a.x + w1 * b.x, w0 * a.y + w1 * b.y,
              w0 * a.z + w1 * b.z, w0 * a.w + w1 * b.w};
  *(float4*)(out + (size_t)tkn * D_DIM + c) = o;
}

// ================= fallback (round-0) kernels, small-ws path =================
__device__ __forceinline__ void stage_bt(const float* __restrict__ Wt, int ldw,
                                         unsigned short* Bs, int tid) {
#pragma unroll
  for (int it = 0; it < 4; it++) {
    const int kp = (tid & 7) + it * 8;
    const int nq = tid >> 3;
    const float* p = Wt + (size_t)(2 * kp) * ldw + nq * 4;
    const float4 va = *(const float4*)p;
    const float4 vb = *(const float4*)(p + ldw);
    unsigned short* b = Bs + (nq * 4) * LDK + 2 * kp;
    *(unsigned*)(b)           = pack_trunc(va.x, vb.x);
    *(unsigned*)(b + LDK)     = pack_trunc(va.y, vb.y);
    *(unsigned*)(b + 2 * LDK) = pack_trunc(va.z, vb.z);
    *(unsigned*)(b + 3 * LDK) = pack_trunc(va.w, vb.w);
  }
}

__global__ __launch_bounds__(256, 2) void gemm1_fb(
    const float* __restrict__ x, const float* __restrict__ wi0,
    const float* __restrict__ wi1, const int* __restrict__ sorted_flat,
    const int* __restrict__ tile_meta, unsigned short* __restrict__ h) {
  __shared__ unsigned short As[128 * LDK];
  __shared__ unsigned short B0s[128 * LDK];
  __shared__ unsigned short B1s[128 * LDK];
  __shared__ int tok[128];
  const int tile = blockIdx.x;
  if (tile >= tile_meta[0]) return;
  const int row0 = tile_meta[1 + 3 * tile];
  const int rowEnd = tile_meta[2 + 3 * tile];
  const int e = tile_meta[3 + 3 * tile];
  const int n0 = blockIdx.y * 128;
  const float* W0 = wi0 + (size_t)e * D_DIM * F_DIM;
  const float* W1 = wi1 + (size_t)e * D_DIM * F_DIM;
  const int tid = threadIdx.x;
  if (tid < 128) {
    int r = row0 + tid; if (r > ROWS - 1) r = ROWS - 1;
    tok[tid] = sorted_flat[r] >> 1;
  }
  f32x4 acc0[4][4], acc1[4][4];
#pragma unroll
  for (int i = 0; i < 4; i++)
#pragma unroll
    for (int j = 0; j < 4; j++) { acc0[i][j] = 0.f; acc1[i][j] = 0.f; }
  const int lane = tid & 63, wv = tid >> 6;
  const int wm = (wv & 1) * 64, wn = (wv >> 1) * 64;
  const int lm = lane & 15, lq = lane >> 4;
  for (int k0 = 0; k0 < D_DIM; k0 += 64) {
    __syncthreads();
#pragma unroll
    for (int i = 0; i < 8; i++) {
      int idx = tid + i * 256;
      int m = idx >> 4, kq = idx & 15;
      float4 v = *(const float4*)(x + (size_t)tok[m] * D_DIM + k0 + kq * 4);
      *(uint2*)&As[m * LDK + kq * 4] =
          make_uint2(pack_trunc(v.x, v.y), pack_trunc(v.z, v.w));
    }
    stage_bt(W0 + (size_t)k0 * F_DIM + n0, F_DIM, B0s, tid);
    stage_bt(W1 + (size_t)k0 * F_DIM + n0, F_DIM, B1s, tid);
    __syncthreads();
#pragma unroll
    for (int ks = 0; ks < 64; ks += 32) {
      s16x8 af[4], b0[4], b1[4];
#pragma unroll
      for (int t = 0; t < 4; t++) {
        af[t] = *(const s16x8*)&As[(wm + t * 16 + lm) * LDK + ks + lq * 8];
        b0[t] = *(const s16x8*)&B0s[(wn + t * 16 + lm) * LDK + ks + lq * 8];
        b1[t] = *(const s16x8*)&B1s[(wn + t * 16 + lm) * LDK + ks + lq * 8];
      }
#pragma unroll
      for (int im = 0; im < 4; im++)
#pragma unroll
        for (int in = 0; in < 4; in++) {
          acc0[im][in] = __builtin_amdgcn_mfma_f32_16x16x32_bf16(
              af[im], b0[in], acc0[im][in], 0, 0, 0);
          acc1[im][in] = __builtin_amdgcn_mfma_f32_16x16x32_bf16(
              af[im], b1[in], acc1[im][in], 0, 0, 0);
        }
    }
  }
#pragma unroll
  for (int im = 0; im < 4; im++) {
    int gmB = row0 + wm + im * 16 + lq * 4;
#pragma unroll
    for (int in = 0; in < 4; in++) {
      int gn = n0 + wn + in * 16 + lm;
#pragma unroll
      for (int r = 0; r < 4; r++) {
        int gm = gmB + r;
        if (gm < rowEnd) {
          float g = acc0[im][in][r];
          float s = g / (1.f + __expf(-g));
          h[(size_t)gm * F_DIM + gn] = bf_rn(s * acc1[im][in][r]);
        }
      }
    }
  }
}

__global__ __launch_bounds__(256, 3) void gemm2_fb(
    const unsigned short* __restrict__ h, const float* __restrict__ wo,
    const float* __restrict__ tw, const int* __restrict__ sorted_flat,
    const int* __restrict__ tile_meta, float* __restrict__ out) {
  __shared__ unsigned short As[128 * LDK];
  __shared__ unsigned short Bs[128 * LDK];
  __shared__ int sTok[128];
  __shared__ float sWgt[128];
  const int tile = blockIdx.x;
  if (tile >= tile_meta[0]) return;
  const int row0 = tile_meta[1 + 3 * tile];
  const int rowEnd = tile_meta[2 + 3 * tile];
  const int e = tile_meta[3 + 3 * tile];
  const int n0 = blockIdx.y * 128;
  const float* W = wo + (size_t)e * F_DIM * D_DIM;
  const int tid = threadIdx.x;
  if (tid < 128) {
    int r = row0 + tid; if (r > ROWS - 1) r = ROWS - 1;
    int fl = sorted_flat[r];
    sTok[tid] = fl >> 1;
    sWgt[tid] = tw[fl];
  }
  f32x4 acc[4][4];
#pragma unroll
  for (int i = 0; i < 4; i++)
#pragma unroll
    for (int j = 0; j < 4; j++) acc[i][j] = 0.f;
  const int lane = tid & 63, wv = tid >> 6;
  const int wm = (wv & 1) * 64, wn = (wv >> 1) * 64;
  const int lm = lane & 15, lq = lane >> 4;
  for (int k0 = 0; k0 < F_DIM; k0 += 64) {
    __syncthreads();
#pragma unroll
    for (int i = 0; i < 8; i++) {
      int idx = tid + i * 256;
      int m = idx >> 4, kq = idx & 15;
      int gm = row0 + m; if (gm > ROWS - 1) gm = ROWS - 1;
      *(uint2*)&As[m * LDK + kq * 4] =
          *(const uint2*)(h + (size_t)gm * F_DIM + k0 + kq * 4);
    }
    stage_bt(W + (size_t)k0 * D_DIM + n0, D_DIM, Bs, tid);
    __syncthreads();
#pragma unroll
    for (int ks = 0; ks < 64; ks += 32) {
      s16x8 af[4], bf[4];
#pragma unroll
      for (int t = 0; t < 4; t++) {
        af[t] = *(const s16x8*)&As[(wm + t * 16 + lm) * LDK + ks + lq * 8];
        bf[t] = *(const s16x8*)&Bs[(wn + t * 16 + lm) * LDK + ks + lq * 8];
      }
#pragma unroll
      for (int im = 0; im < 4; im++)
#pragma unroll
        for (int in = 0; in < 4; in++)
          acc[im][in] = __builtin_amdgcn_mfma_f32_16x16x32_bf16(
              af[im], bf[in], acc[im][in], 0, 0, 0);
    }
  }
#pragma unroll
  for (int im = 0; im < 4; im++) {
    int lrB = wm + im * 16 + lq * 4;
#pragma unroll
    for (int in = 0; in < 4; in++) {
      int gn = n0 + wn + in * 16 + lm;
#pragma unroll
      for (int r = 0; r < 4; r++) {
        int lr = lrB + r;
        int gm = row0 + lr;
        if (gm < rowEnd)
          atomicAdd(out + (size_t)sTok[lr] * D_DIM + gn, sWgt[lr] * acc[im][in][r]);
      }
    }
  }
}

extern "C" void kernel_launch(void* const* d_in, const int* in_sizes, int n_in,
                              void* d_out, int out_size, void* d_ws, size_t ws_size,
                              hipStream_t stream) {
  const float* x   = (const float*)d_in[0];
  const float* tw  = (const float*)d_in[1];
  const int*   ids = (const int*)d_in[2];
  const float* wi0 = (const float*)d_in[3];
  const float* wi1 = (const float*)d_in[4];
  const float* wo  = (const float*)d_in[5];
  float* out = (float*)d_out;

  int* tile_meta = (int*)d_ws;            // 256 ints
  int* sorted_flat = tile_meta + 256;     // 4096 ints
  int* unsort = sorted_flat + ROWS;       // 4096 ints (ends < 64KB)

  const size_t MB = 1024 * 1024;
  const size_t XS_OFF = 64 * 1024;
  const size_t H_OFF  = XS_OFF + 8 * MB;
  const size_t Y_OFF  = H_OFF + 16 * MB;
  const size_t NEED   = Y_OFF + 16 * MB;   // ~40.06 MB

  route_kernel<<<1, 512, 0, stream>>>(ids, sorted_flat, unsort, tile_meta);
  if (ws_size >= NEED) {
    unsigned short* xs = (unsigned short*)((char*)d_ws + XS_OFF);
    unsigned short* h  = (unsigned short*)((char*)d_ws + H_OFF);
    float* y = (float*)((char*)d_ws + Y_OFF);

    gather_kernel<<<ROWS, 256, 0, stream>>>(x, sorted_flat, xs);
    gemm1_kernel<<<dim3(MAXTILE, F_DIM / 64), 256, 0, stream>>>(xs, wi0, wi1,
                                                                tile_meta, h);
    gemm2_kernel<<<dim3(MAXTILE, D_DIM / 64), 256, 0, stream>>>(h, wo,
                                                                tile_meta, y);
    combine_kernel<<<ROWS / 2, 256, 0, stream>>>(y, tw, unsort, out);
  } else {
    unsigned short* h = (unsigned short*)((char*)d_ws + XS_OFF);
    zero_kernel<<<(out_size / 4 + 255) / 256, 256, 0, stream>>>((float4*)out,
                                                                out_size / 4);
    gemm1_fb<<<dim3(MAXTILE, F_DIM / 128), 256, 0, stream>>>(x, wi0, wi1,
                                                             sorted_flat,
                                                             tile_meta, h);
    gemm2_fb<<<dim3(MAXTILE, D_DIM / 128), 256, 0, stream>>>(h, wo, tw,
                                                             sorted_flat,
                                                             tile_meta, out);
  }
}

// Round 5
// 315.437 us; speedup vs baseline: 1.2514x; 1.2514x over previous
//
#include <hip/hip_runtime.h>
#include <hip/hip_bf16.h>

// EPMoE: E=8, K=2, D=1024, F=2048, T=2048, ROWS=4096.
// R5: revert to R1 architecture (convT 256x128 + bf16 GEMMs; R3's NT/remap and
// R4's fp32-staging fusion both falsified: R4 showed fp32 B-staging multiplies
// weight traffic by m-tile reuse -> FETCH 304MB, gemm1 142us). New in R5:
//  - route + out-zero folded INTO the convT launch (blockIdx.y==24: route on
//    one block; y==25: zero out) — hides ~2 serial launches under convT.
//  - combine fused into gemm2 via atomicAdd epilogue (gemm2_fb-proven):
//    out[tok] += tw*acc. Kills the 16MB y buffer round-trip + combine launch.
// Ledger: R1 = 320us with ~60us of launch gaps + small kernels; this round
// attacks that overhead, not kernel micro-structure.
// convT facts (R0/R1/R3): pinned at ~86us / 3.3 TB/s effective; not
// granularity-bound (256B vs 512B identical), NT stores don't change FETCH.
// GEMM LDS swizzle: [R][64] bf16 rows = 128B = 32 banks; physical 16B chunk j
// of row m holds logical chunk j^(m&7) (applied on global source address;
// global_load_lds dst stays lane-contiguous).
// gemm1/2 accumulators: 64/32 AGPR — fits waves budget (prior lesson: 128
// AGPR + 120 VGPR at w=3 spilled -> 391MB scratch traffic).

#define D_DIM 1024
#define F_DIM 2048
#define ROWS 4096
#define MAXTILE 40
#define LDK 72   // fallback-path LDS k-stride

using f32x4 = __attribute__((ext_vector_type(4))) float;
using s16x8 = __attribute__((ext_vector_type(8))) short;

__device__ __forceinline__ unsigned pack_trunc(float lo, float hi) {
  return (__float_as_uint(lo) >> 16) | (__float_as_uint(hi) & 0xffff0000u);
}
__device__ __forceinline__ unsigned short bf_rn(float f) {
  unsigned u = __float_as_uint(f);
  u += 0x7fffu + ((u >> 16) & 1u);
  return (unsigned short)(u >> 16);
}
__device__ __forceinline__ unsigned pack_rn(float lo, float hi) {
  return (unsigned)bf_rn(lo) | ((unsigned)bf_rn(hi) << 16);
}

typedef const __attribute__((address_space(1))) void* gp_t;
typedef __attribute__((address_space(3))) void* lp_t;
__device__ __forceinline__ void load16(const void* g, void* l) {
  __builtin_amdgcn_global_load_lds((gp_t)g, (lp_t)l, 16, 0, 0);
}

// -------- routing body: stable counting sort by expert (ids staged in LDS) ----
// sid: 4096 ints, cnt: 8 ints, off: 9 ints (caller provides LDS).
__device__ __forceinline__ void route_body(const int* __restrict__ ids,
                                           int* __restrict__ sorted_flat,
                                           int* __restrict__ unsort,
                                           int* __restrict__ tile_meta,
                                           int* sid, int* cnt, int* off) {
  const int tid = threadIdx.x;
#pragma unroll
  for (int j = 0; j < 2; j++) {
    int idx = tid + j * 512;                    // int4 index
    *(int4*)&sid[idx * 4] = *(const int4*)&ids[idx * 4];
  }
  __syncthreads();
  const int w = tid >> 6, lane = tid & 63;
  int c = 0;
  for (int base = 0; base < ROWS; base += 64)
    c += __popcll(__ballot(sid[base + lane] == w));
  if (lane == 0) cnt[w] = c;
  __syncthreads();
  if (tid == 0) {
    int o = 0;
    for (int e = 0; e < 8; e++) { off[e] = o; o += cnt[e]; }
    off[8] = o;
    int nT = 0;
    for (int e = 0; e < 8; e++) {
      for (int r0 = off[e]; r0 < off[e + 1]; r0 += 128) {
        tile_meta[1 + 3 * nT] = r0;
        tile_meta[2 + 3 * nT] = off[e + 1];
        tile_meta[3 + 3 * nT] = e;
        nT++;
      }
    }
    tile_meta[0] = nT;
  }
  __syncthreads();
  int pos = off[w];
  const unsigned long long below = (1ull << lane) - 1ull;
  for (int base = 0; base < ROWS; base += 64) {
    unsigned long long m = __ballot(sid[base + lane] == w);
    if (sid[base + lane] == w) {
      int p = pos + __popcll(m & below);
      sorted_flat[p] = base + lane;
      unsort[base + lane] = p;
    }
    pos += __popcll(m);
  }
}

// standalone route (fallback path)
__global__ __launch_bounds__(512) void route_kernel(const int* __restrict__ ids,
                                                    int* __restrict__ sorted_flat,
                                                    int* __restrict__ unsort,
                                                    int* __restrict__ tile_meta) {
  __shared__ int sid[ROWS];
  __shared__ int cnt[8];
  __shared__ int off[9];
  route_body(ids, sorted_flat, unsort, tile_meta, sid, cnt, off);
}

__global__ void zero_kernel(float4* __restrict__ p, int n4) {
  int i = blockIdx.x * blockDim.x + threadIdx.x;
  if (i < n4) p[i] = float4{0.f, 0.f, 0.f, 0.f};
}

// ------- convT mega-launch: grid (64, 26) x 512 threads -------
// y<24: fp32 W [E][Kd][Nd] -> bf16 [E][Nd][Kd], 256(k)x128(n) tile per block.
//   Reads 512B contiguous per 32-lane group; LDS [128 n][128 kpair] uints =
//   64KB, quad-XOR swizzle; uint4 drains 512B contiguous per 32-lane group.
// y==24: route (block x==0 only; LDS aliased onto t).
// y==25: zero the output buffer (fused-combine target), grid-stride.
__global__ __launch_bounds__(512, 4) void convT_lds(
    const float* __restrict__ wi0, const float* __restrict__ wi1,
    const float* __restrict__ wo, unsigned short* __restrict__ w0T,
    unsigned short* __restrict__ w1T, unsigned short* __restrict__ woT,
    const int* __restrict__ ids, int* __restrict__ sorted_flat,
    int* __restrict__ unsort, int* __restrict__ tile_meta,
    float4* __restrict__ out4) {
  __shared__ unsigned t[128 * 128];  // [n][phys kpair], 64KB
  const int z = blockIdx.y;          // 0..25
  if (z == 24) {                     // ---- route ----
    if (blockIdx.x != 0) return;
    route_body(ids, sorted_flat, unsort, tile_meta,
               (int*)t, (int*)&t[4096], (int*)&t[4104]);
    return;
  }
  if (z == 25) {                     // ---- zero out (2048*1024 f32) ----
    const int n4 = (ROWS / 2) * D_DIM / 4;         // 524288 float4
    for (int i = blockIdx.x * 512 + threadIdx.x; i < n4; i += 64 * 512)
      out4[i] = float4{0.f, 0.f, 0.f, 0.f};
    return;
  }
  const int which = z >> 3, e = z & 7;
  const float* S;
  unsigned short* Dp;
  int Kd, Nd, nbits;
  if (which == 0)      { S = wi0; Dp = w0T; Kd = D_DIM; Nd = F_DIM; nbits = 4; }
  else if (which == 1) { S = wi1; Dp = w1T; Kd = D_DIM; Nd = F_DIM; nbits = 4; }
  else                 { S = wo;  Dp = woT; Kd = F_DIM; Nd = D_DIM; nbits = 3; }
  S  += (size_t)e * Kd * Nd;
  Dp += (size_t)e * Kd * Nd;
  const int n0 = (blockIdx.x & ((1 << nbits) - 1)) * 128;
  const int k0 = (blockIdx.x >> nbits) * 256;
  const int tid = threadIdx.x;
  const int nc  = tid & 31;    // float4 n-chunk (4 n each)
  const int kpb = tid >> 5;    // kpair base 0..15

  // ---- issue all 16 float4 loads (8 k-pair rounds x 2 rows) up front ----
  float4 v[8][2];
#pragma unroll
  for (int r = 0; r < 8; r++) {
    const int kp = kpb + r * 16;  // 0..127
    const float* p = S + (size_t)(k0 + 2 * kp) * Nd + n0 + nc * 4;
    v[r][0] = *(const float4*)p;
    v[r][1] = *(const float4*)(p + Nd);
  }
  __builtin_amdgcn_sched_barrier(0);  // keep packs from sinking above loads

  // ---- pack k-pairs -> bf16x2, write LDS transposed (swizzled) ----
#pragma unroll
  for (int r = 0; r < 8; r++) {
    const int kp = kpb + r * 16;
    const int q = kp >> 2, ql = kp & 3;
    const int col = ((q ^ (nc & 7)) << 2) | ql;  // phys uint within n-row
    t[(4 * nc + 0) * 128 + col] = pack_rn(v[r][0].x, v[r][1].x);
    t[(4 * nc + 1) * 128 + col] = pack_rn(v[r][0].y, v[r][1].y);
    t[(4 * nc + 2) * 128 + col] = pack_rn(v[r][0].z, v[r][1].z);
    t[(4 * nc + 3) * 128 + col] = pack_rn(v[r][0].w, v[r][1].w);
  }
  __syncthreads();

  // ---- drain: uint4 per thread, 512B contiguous per 32-lane group ----
  const int c = tid & 31;  // kpair-quad 0..31 (16B chunk within 512B k-run)
#pragma unroll
  for (int s = 0; s < 8; s++) {
    const int n = (tid >> 5) + s * 16;
    const int col = (c ^ ((n >> 2) & 7)) << 2;
    const unsigned* qp = &t[n * 128 + col];
    uint4 o = make_uint4(qp[0], qp[1], qp[2], qp[3]);
    *(uint4*)(Dp + (size_t)(n0 + n) * Kd + k0 + c * 8) = o;
  }
}

// ---------------- gather: x fp32 -> x_sorted bf16 ----------------
__global__ __launch_bounds__(256) void gather_kernel(const float* __restrict__ x,
                                                     const int* __restrict__ sorted_flat,
                                                     unsigned short* __restrict__ xs) {
  const int r = blockIdx.x;
  const int tok = sorted_flat[r] >> 1;
  const float4 v = *(const float4*)(x + (size_t)tok * D_DIM + threadIdx.x * 4);
  *(uint2*)(xs + (size_t)r * D_DIM + threadIdx.x * 4) =
      make_uint2(pack_rn(v.x, v.y), pack_rn(v.z, v.w));
}

// swizzled frag address: physical chunk = logical_chunk ^ (row&7)
__device__ __forceinline__ int sw(int row, int chunk) {
  return row * 64 + ((chunk ^ (row & 7)) << 3);
}

// ------- GEMM1: xs @ (w0T,w1T) -> h = silu(g0)*g1.  128(m) x 64(n) tiles -------
__global__ __launch_bounds__(256, 3) void gemm1_kernel(
    const unsigned short* __restrict__ xs, const unsigned short* __restrict__ w0T,
    const unsigned short* __restrict__ w1T, const int* __restrict__ tile_meta,
    unsigned short* __restrict__ h) {
  __shared__ unsigned short As[128 * 64];
  __shared__ unsigned short B0s[64 * 64];
  __shared__ unsigned short B1s[64 * 64];
  const int tile = blockIdx.x;
  if (tile >= tile_meta[0]) return;
  const int row0 = tile_meta[1 + 3 * tile];
  const int rowEnd = tile_meta[2 + 3 * tile];
  const int e = tile_meta[3 + 3 * tile];
  const int n0 = blockIdx.y * 64;
  const unsigned short* W0 = w0T + ((size_t)e * F_DIM + n0) * D_DIM;
  const unsigned short* W1 = w1T + ((size_t)e * F_DIM + n0) * D_DIM;

  const int tid = threadIdx.x;
  const int lane = tid & 63, wv = tid >> 6;
  const int wm = (wv & 1) * 64, wn = (wv >> 1) * 32;
  const int lm = lane & 15, lq = lane >> 4;
  const int srow = lane >> 3;                       // staging row-in-chunk
  const int skk = ((lane & 7) ^ srow) << 3;         // swizzled source elem off

  f32x4 acc0[4][2], acc1[4][2];
#pragma unroll
  for (int i = 0; i < 4; i++)
#pragma unroll
    for (int j = 0; j < 2; j++) { acc0[i][j] = 0.f; acc1[i][j] = 0.f; }

  for (int k0 = 0; k0 < D_DIM; k0 += 64) {
    __syncthreads();
#pragma unroll
    for (int r = 0; r < 4; r++) {                 // A: 16 chunks, 4/wave
      const int c = r * 4 + wv;
      const int m = c * 8 + srow;
      int mc = row0 + m; if (mc > ROWS - 1) mc = ROWS - 1;
      load16(xs + (size_t)mc * D_DIM + k0 + skk, (char*)As + c * 1024);
    }
#pragma unroll
    for (int r = 0; r < 2; r++) {                 // B0,B1: 8 chunks, 2/wave
      const int c = r * 4 + wv;
      const int m = c * 8 + srow;
      load16(W0 + (size_t)m * D_DIM + k0 + skk, (char*)B0s + c * 1024);
      load16(W1 + (size_t)m * D_DIM + k0 + skk, (char*)B1s + c * 1024);
    }
    __syncthreads();
#pragma unroll
    for (int ks = 0; ks < 64; ks += 32) {
      const int cb = (ks >> 3) + lq;
      s16x8 af[4], b0[2], b1[2];
#pragma unroll
      for (int t = 0; t < 4; t++)
        af[t] = *(const s16x8*)&As[sw(wm + t * 16 + lm, cb)];
#pragma unroll
      for (int t = 0; t < 2; t++) {
        b0[t] = *(const s16x8*)&B0s[sw(wn + t * 16 + lm, cb)];
        b1[t] = *(const s16x8*)&B1s[sw(wn + t * 16 + lm, cb)];
      }
#pragma unroll
      for (int im = 0; im < 4; im++)
#pragma unroll
        for (int in = 0; in < 2; in++) {
          acc0[im][in] = __builtin_amdgcn_mfma_f32_16x16x32_bf16(
              af[im], b0[in], acc0[im][in], 0, 0, 0);
          acc1[im][in] = __builtin_amdgcn_mfma_f32_16x16x32_bf16(
              af[im], b1[in], acc1[im][in], 0, 0, 0);
        }
    }
  }
#pragma unroll
  for (int im = 0; im < 4; im++) {
    int gmB = row0 + wm + im * 16 + lq * 4;
#pragma unroll
    for (int in = 0; in < 2; in++) {
      int gn = n0 + wn + in * 16 + lm;
#pragma unroll
      for (int r = 0; r < 4; r++) {
        int gm = gmB + r;
        if (gm < rowEnd) {
          float g = acc0[im][in][r];
          float s = g / (1.f + __expf(-g));
          h[(size_t)gm * F_DIM + gn] = bf_rn(s * acc1[im][in][r]);
        }
      }
    }
  }
}

// --- GEMM2 (+fused combine): h @ woT, atomicAdd tw*acc into out[tok] ---
// 128(m) x 64(n) tiles; epilogue pattern proven in gemm2_fb.
__global__ __launch_bounds__(256, 4) void gemm2_kernel(
    const unsigned short* __restrict__ h, const unsigned short* __restrict__ woT,
    const float* __restrict__ tw, const int* __restrict__ sorted_flat,
    const int* __restrict__ tile_meta, float* __restrict__ out) {
  __shared__ unsigned short As[128 * 64];
  __shared__ unsigned short Bs[64 * 64];
  __shared__ int sTok[128];
  __shared__ float sWgt[128];
  const int tile = blockIdx.x;
  if (tile >= tile_meta[0]) return;
  const int row0 = tile_meta[1 + 3 * tile];
  const int rowEnd = tile_meta[2 + 3 * tile];
  const int e = tile_meta[3 + 3 * tile];
  const int n0 = blockIdx.y * 64;
  const unsigned short* W = woT + ((size_t)e * D_DIM + n0) * F_DIM;

  const int tid = threadIdx.x;
  if (tid < 128) {
    int r = row0 + tid; if (r > ROWS - 1) r = ROWS - 1;
    int fl = sorted_flat[r];
    sTok[tid] = fl >> 1;
    sWgt[tid] = tw[fl];
  }
  const int lane = tid & 63, wv = tid >> 6;
  const int wm = (wv & 1) * 64, wn = (wv >> 1) * 32;
  const int lm = lane & 15, lq = lane >> 4;
  const int srow = lane >> 3;
  const int skk = ((lane & 7) ^ srow) << 3;

  f32x4 acc[4][2];
#pragma unroll
  for (int i = 0; i < 4; i++)
#pragma unroll
    for (int j = 0; j < 2; j++) acc[i][j] = 0.f;

  for (int k0 = 0; k0 < F_DIM; k0 += 64) {
    __syncthreads();
#pragma unroll
    for (int r = 0; r < 4; r++) {
      const int c = r * 4 + wv;
      const int m = c * 8 + srow;
      int mc = row0 + m; if (mc > ROWS - 1) mc = ROWS - 1;
      load16(h + (size_t)mc * F_DIM + k0 + skk, (char*)As + c * 1024);
    }
#pragma unroll
    for (int r = 0; r < 2; r++) {
      const int c = r * 4 + wv;
      const int m = c * 8 + srow;
      load16(W + (size_t)m * F_DIM + k0 + skk, (char*)Bs + c * 1024);
    }
    __syncthreads();
#pragma unroll
    for (int ks = 0; ks < 64; ks += 32) {
      const int cb = (ks >> 3) + lq;
      s16x8 af[4], bf[2];
#pragma unroll
      for (int t = 0; t < 4; t++)
        af[t] = *(const s16x8*)&As[sw(wm + t * 16 + lm, cb)];
#pragma unroll
      for (int t = 0; t < 2; t++)
        bf[t] = *(const s16x8*)&Bs[sw(wn + t * 16 + lm, cb)];
#pragma unroll
      for (int im = 0; im < 4; im++)
#pragma unroll
        for (int in = 0; in < 2; in++)
          acc[im][in] = __builtin_amdgcn_mfma_f32_16x16x32_bf16(
              af[im], bf[in], acc[im][in], 0, 0, 0);
    }
  }
#pragma unroll
  for (int im = 0; im < 4; im++) {
    int lrB = wm + im * 16 + lq * 4;
#pragma unroll
    for (int in = 0; in < 2; in++) {
      int gn = n0 + wn + in * 16 + lm;
#pragma unroll
      for (int r = 0; r < 4; r++) {
        int lr = lrB + r;
        int gm = row0 + lr;
        if (gm < rowEnd)
          atomicAdd(out + (size_t)sTok[lr] * D_DIM + gn,
                    sWgt[lr] * acc[im][in][r]);
      }
    }
  }
}

// ================= fallback (round-0) kernels, small-ws path =================
__device__ __forceinline__ void stage_bt(const float* __restrict__ Wt, int ldw,
                                         unsigned short* Bs, int tid) {
#pragma unroll
  for (int it = 0; it < 4; it++) {
    const int kp = (tid & 7) + it * 8;
    const int nq = tid >> 3;
    const float* p = Wt + (size_t)(2 * kp) * ldw + nq * 4;
    const float4 va = *(const float4*)p;
    const float4 vb = *(const float4*)(p + ldw);
    unsigned short* b = Bs + (nq * 4) * LDK + 2 * kp;
    *(unsigned*)(b)           = pack_trunc(va.x, vb.x);
    *(unsigned*)(b + LDK)     = pack_trunc(va.y, vb.y);
    *(unsigned*)(b + 2 * LDK) = pack_trunc(va.z, vb.z);
    *(unsigned*)(b + 3 * LDK) = pack_trunc(va.w, vb.w);
  }
}

__global__ __launch_bounds__(256, 2) void gemm1_fb(
    const float* __restrict__ x, const float* __restrict__ wi0,
    const float* __restrict__ wi1, const int* __restrict__ sorted_flat,
    const int* __restrict__ tile_meta, unsigned short* __restrict__ h) {
  __shared__ unsigned short As[128 * LDK];
  __shared__ unsigned short B0s[128 * LDK];
  __shared__ unsigned short B1s[128 * LDK];
  __shared__ int tok[128];
  const int tile = blockIdx.x;
  if (tile >= tile_meta[0]) return;
  const int row0 = tile_meta[1 + 3 * tile];
  const int rowEnd = tile_meta[2 + 3 * tile];
  const int e = tile_meta[3 + 3 * tile];
  const int n0 = blockIdx.y * 128;
  const float* W0 = wi0 + (size_t)e * D_DIM * F_DIM;
  const float* W1 = wi1 + (size_t)e * D_DIM * F_DIM;
  const int tid = threadIdx.x;
  if (tid < 128) {
    int r = row0 + tid; if (r > ROWS - 1) r = ROWS - 1;
    tok[tid] = sorted_flat[r] >> 1;
  }
  f32x4 acc0[4][4], acc1[4][4];
#pragma unroll
  for (int i = 0; i < 4; i++)
#pragma unroll
    for (int j = 0; j < 4; j++) { acc0[i][j] = 0.f; acc1[i][j] = 0.f; }
  const int lane = tid & 63, wv = tid >> 6;
  const int wm = (wv & 1) * 64, wn = (wv >> 1) * 64;
  const int lm = lane & 15, lq = lane >> 4;
  for (int k0 = 0; k0 < D_DIM; k0 += 64) {
    __syncthreads();
#pragma unroll
    for (int i = 0; i < 8; i++) {
      int idx = tid + i * 256;
      int m = idx >> 4, kq = idx & 15;
      float4 v = *(const float4*)(x + (size_t)tok[m] * D_DIM + k0 + kq * 4);
      *(uint2*)&As[m * LDK + kq * 4] =
          make_uint2(pack_trunc(v.x, v.y), pack_trunc(v.z, v.w));
    }
    stage_bt(W0 + (size_t)k0 * F_DIM + n0, F_DIM, B0s, tid);
    stage_bt(W1 + (size_t)k0 * F_DIM + n0, F_DIM, B1s, tid);
    __syncthreads();
#pragma unroll
    for (int ks = 0; ks < 64; ks += 32) {
      s16x8 af[4], b0[4], b1[4];
#pragma unroll
      for (int t = 0; t < 4; t++) {
        af[t] = *(const s16x8*)&As[(wm + t * 16 + lm) * LDK + ks + lq * 8];
        b0[t] = *(const s16x8*)&B0s[(wn + t * 16 + lm) * LDK + ks + lq * 8];
        b1[t] = *(const s16x8*)&B1s[(wn + t * 16 + lm) * LDK + ks + lq * 8];
      }
#pragma unroll
      for (int im = 0; im < 4; im++)
#pragma unroll
        for (int in = 0; in < 4; in++) {
          acc0[im][in] = __builtin_amdgcn_mfma_f32_16x16x32_bf16(
              af[im], b0[in], acc0[im][in], 0, 0, 0);
          acc1[im][in] = __builtin_amdgcn_mfma_f32_16x16x32_bf16(
              af[im], b1[in], acc1[im][in], 0, 0, 0);
        }
    }
  }
#pragma unroll
  for (int im = 0; im < 4; im++) {
    int gmB = row0 + wm + im * 16 + lq * 4;
#pragma unroll
    for (int in = 0; in < 4; in++) {
      int gn = n0 + wn + in * 16 + lm;
#pragma unroll
      for (int r = 0; r < 4; r++) {
        int gm = gmB + r;
        if (gm < rowEnd) {
          float g = acc0[im][in][r];
          float s = g / (1.f + __expf(-g));
          h[(size_t)gm * F_DIM + gn] = bf_rn(s * acc1[im][in][r]);
        }
      }
    }
  }
}

__global__ __launch_bounds__(256, 3) void gemm2_fb(
    const unsigned short* __restrict__ h, const float* __restrict__ wo,
    const float* __restrict__ tw, const int* __restrict__ sorted_flat,
    const int* __restrict__ tile_meta, float* __restrict__ out) {
  __shared__ unsigned short As[128 * LDK];
  __shared__ unsigned short Bs[128 * LDK];
  __shared__ int sTok[128];
  __shared__ float sWgt[128];
  const int tile = blockIdx.x;
  if (tile >= tile_meta[0]) return;
  const int row0 = tile_meta[1 + 3 * tile];
  const int rowEnd = tile_meta[2 + 3 * tile];
  const int e = tile_meta[3 + 3 * tile];
  const int n0 = blockIdx.y * 128;
  const float* W = wo + (size_t)e * F_DIM * D_DIM;
  const int tid = threadIdx.x;
  if (tid < 128) {
    int r = row0 + tid; if (r > ROWS - 1) r = ROWS - 1;
    int fl = sorted_flat[r];
    sTok[tid] = fl >> 1;
    sWgt[tid] = tw[fl];
  }
  f32x4 acc[4][4];
#pragma unroll
  for (int i = 0; i < 4; i++)
#pragma unroll
    for (int j = 0; j < 4; j++) acc[i][j] = 0.f;
  const int lane = tid & 63, wv = tid >> 6;
  const int wm = (wv & 1) * 64, wn = (wv >> 1) * 64;
  const int lm = lane & 15, lq = lane >> 4;
  for (int k0 = 0; k0 < F_DIM; k0 += 64) {
    __syncthreads();
#pragma unroll
    for (int i = 0; i < 8; i++) {
      int idx = tid + i * 256;
      int m = idx >> 4, kq = idx & 15;
      int gm = row0 + m; if (gm > ROWS - 1) gm = ROWS - 1;
      *(uint2*)&As[m * LDK + kq * 4] =
          *(const uint2*)(h + (size_t)gm * F_DIM + k0 + kq * 4);
    }
    stage_bt(W + (size_t)k0 * D_DIM + n0, D_DIM, Bs, tid);
    __syncthreads();
#pragma unroll
    for (int ks = 0; ks < 64; ks += 32) {
      s16x8 af[4], bf[4];
#pragma unroll
      for (int t = 0; t < 4; t++) {
        af[t] = *(const s16x8*)&As[(wm + t * 16 + lm) * LDK + ks + lq * 8];
        bf[t] = *(const s16x8*)&Bs[(wn + t * 16 + lm) * LDK + ks + lq * 8];
      }
#pragma unroll
      for (int im = 0; im < 4; im++)
#pragma unroll
        for (int in = 0; in < 4; in++)
          acc[im][in] = __builtin_amdgcn_mfma_f32_16x16x32_bf16(
              af[im], bf[in], acc[im][in], 0, 0, 0);
    }
  }
#pragma unroll
  for (int im = 0; im < 4; im++) {
    int lrB = wm + im * 16 + lq * 4;
#pragma unroll
    for (int in = 0; in < 4; in++) {
      int gn = n0 + wn + in * 16 + lm;
#pragma unroll
      for (int r = 0; r < 4; r++) {
        int lr = lrB + r;
        int gm = row0 + lr;
        if (gm < rowEnd)
          atomicAdd(out + (size_t)sTok[lr] * D_DIM + gn, sWgt[lr] * acc[im][in][r]);
      }
    }
  }
}

extern "C" void kernel_launch(void* const* d_in, const int* in_sizes, int n_in,
                              void* d_out, int out_size, void* d_ws, size_t ws_size,
                              hipStream_t stream) {
  const float* x   = (const float*)d_in[0];
  const float* tw  = (const float*)d_in[1];
  const int*   ids = (const int*)d_in[2];
  const float* wi0 = (const float*)d_in[3];
  const float* wi1 = (const float*)d_in[4];
  const float* wo  = (const float*)d_in[5];
  float* out = (float*)d_out;

  int* tile_meta = (int*)d_ws;            // 256 ints
  int* sorted_flat = tile_meta + 256;     // 4096 ints
  int* unsort = sorted_flat + ROWS;       // 4096 ints (ends < 64KB)

  const size_t MB = 1024 * 1024;
  const size_t XS_OFF = 64 * 1024;
  const size_t H_OFF  = XS_OFF + 8 * MB;
  const size_t W0_OFF = H_OFF + 16 * MB;
  const size_t W1_OFF = W0_OFF + 32 * MB;
  const size_t WO_OFF = W1_OFF + 32 * MB;
  const size_t NEED   = WO_OFF + 32 * MB;  // ~120.06 MB

  if (ws_size >= NEED) {
    unsigned short* xs  = (unsigned short*)((char*)d_ws + XS_OFF);
    unsigned short* h   = (unsigned short*)((char*)d_ws + H_OFF);
    unsigned short* w0T = (unsigned short*)((char*)d_ws + W0_OFF);
    unsigned short* w1T = (unsigned short*)((char*)d_ws + W1_OFF);
    unsigned short* woT = (unsigned short*)((char*)d_ws + WO_OFF);

    // route (y=24) + out-zero (y=25) ride along with convT
    convT_lds<<<dim3(64, 26), 512, 0, stream>>>(wi0, wi1, wo, w0T, w1T, woT,
                                                ids, sorted_flat, unsort,
                                                tile_meta, (float4*)out);
    gather_kernel<<<ROWS, 256, 0, stream>>>(x, sorted_flat, xs);
    gemm1_kernel<<<dim3(MAXTILE, F_DIM / 64), 256, 0, stream>>>(xs, w0T, w1T,
                                                                tile_meta, h);
    gemm2_kernel<<<dim3(MAXTILE, D_DIM / 64), 256, 0, stream>>>(h, woT, tw,
                                                                sorted_flat,
                                                                tile_meta, out);
  } else {
    unsigned short* h = (unsigned short*)((char*)d_ws + XS_OFF);
    route_kernel<<<1, 512, 0, stream>>>(ids, sorted_flat, unsort, tile_meta);
    zero_kernel<<<(ROWS / 2 * D_DIM / 4 + 255) / 256, 256, 0, stream>>>(
        (float4*)out, ROWS / 2 * D_DIM / 4);
    gemm1_fb<<<dim3(MAXTILE, F_DIM / 128), 256, 0, stream>>>(x, wi0, wi1,
                                                             sorted_flat,
                                                             tile_meta, h);
    gemm2_fb<<<dim3(MAXTILE, D_DIM / 128), 256, 0, stream>>>(h, wo, tw,
                                                             sorted_flat,
                                                             tile_meta, out);
  }
}

// Round 6
// 313.713 us; speedup vs baseline: 1.2583x; 1.0055x over previous
//
#include <hip/hip_runtime.h>
#include <hip/hip_bf16.h>

// EPMoE: E=8, K=2, D=1024, F=2048, T=2048, ROWS=4096.
// R6: pipeline overlap. Kernel A converts ONLY wi0/wi1 (16 z-slices) +
// route (z=16) + out-zero (z=17). The wo->woT conversion RIDES INSIDE the
// gemm1 launch (grid 72x32: x<40 = gemm1 tiles, x>=40 = 1024 rider blocks
// doing 128k x 128n convT tiles, LDS aliased). gemm1 is MfmaUtil~10% /
// cache-BW-heavy; convT is HBM-streaming -> disjoint resources, riders hide.
// Zero-overlap case is arithmetically neutral (58+114 = 87+85); any overlap
// is pure gain + one fewer launch.
// gemm2 keeps the R5 fused-combine atomicAdd epilogue (out zeroed in A).
// Ledger: R1=320 (convT 87 + gemm1 ~85 + gemm2 ~60 + gather 8 + ~75 gaps),
// R5=315 (route/zero folded, combine fused). Falsified: R1 segment-size
// theory, R3 NT-store/XCD-remap, R4 fp32-B-staging (FETCH 304MB, 142us).
// convT recipe (proven R0/R1): 512B-contiguous reads, LDS transpose with
// row-quad XOR swizzle (key (n>>2)&7 on 16B chunks), uint4 512B drains.
// GEMM LDS swizzle: [R][64] bf16 rows = 128B = 32 banks; physical 16B chunk
// j of row m holds logical chunk j^(m&7) (applied on global source address;
// global_load_lds dst stays lane-contiguous).

#define D_DIM 1024
#define F_DIM 2048
#define ROWS 4096
#define MAXTILE 40
#define LDK 72   // fallback-path LDS k-stride

using f32x4 = __attribute__((ext_vector_type(4))) float;
using s16x8 = __attribute__((ext_vector_type(8))) short;

__device__ __forceinline__ unsigned pack_trunc(float lo, float hi) {
  return (__float_as_uint(lo) >> 16) | (__float_as_uint(hi) & 0xffff0000u);
}
__device__ __forceinline__ unsigned short bf_rn(float f) {
  unsigned u = __float_as_uint(f);
  u += 0x7fffu + ((u >> 16) & 1u);
  return (unsigned short)(u >> 16);
}
__device__ __forceinline__ unsigned pack_rn(float lo, float hi) {
  return (unsigned)bf_rn(lo) | ((unsigned)bf_rn(hi) << 16);
}

typedef const __attribute__((address_space(1))) void* gp_t;
typedef __attribute__((address_space(3))) void* lp_t;
__device__ __forceinline__ void load16(const void* g, void* l) {
  __builtin_amdgcn_global_load_lds((gp_t)g, (lp_t)l, 16, 0, 0);
}

// -------- routing body: stable counting sort by expert (ids staged in LDS) ----
__device__ __forceinline__ void route_body(const int* __restrict__ ids,
                                           int* __restrict__ sorted_flat,
                                           int* __restrict__ unsort,
                                           int* __restrict__ tile_meta,
                                           int* sid, int* cnt, int* off) {
  const int tid = threadIdx.x;
#pragma unroll
  for (int j = 0; j < 2; j++) {
    int idx = tid + j * 512;                    // int4 index
    *(int4*)&sid[idx * 4] = *(const int4*)&ids[idx * 4];
  }
  __syncthreads();
  const int w = tid >> 6, lane = tid & 63;
  int c = 0;
  for (int base = 0; base < ROWS; base += 64)
    c += __popcll(__ballot(sid[base + lane] == w));
  if (lane == 0) cnt[w] = c;
  __syncthreads();
  if (tid == 0) {
    int o = 0;
    for (int e = 0; e < 8; e++) { off[e] = o; o += cnt[e]; }
    off[8] = o;
    int nT = 0;
    for (int e = 0; e < 8; e++) {
      for (int r0 = off[e]; r0 < off[e + 1]; r0 += 128) {
        tile_meta[1 + 3 * nT] = r0;
        tile_meta[2 + 3 * nT] = off[e + 1];
        tile_meta[3 + 3 * nT] = e;
        nT++;
      }
    }
    tile_meta[0] = nT;
  }
  __syncthreads();
  int pos = off[w];
  const unsigned long long below = (1ull << lane) - 1ull;
  for (int base = 0; base < ROWS; base += 64) {
    unsigned long long m = __ballot(sid[base + lane] == w);
    if (sid[base + lane] == w) {
      int p = pos + __popcll(m & below);
      sorted_flat[p] = base + lane;
      unsort[base + lane] = p;
    }
    pos += __popcll(m);
  }
}

// standalone route (fallback path)
__global__ __launch_bounds__(512) void route_kernel(const int* __restrict__ ids,
                                                    int* __restrict__ sorted_flat,
                                                    int* __restrict__ unsort,
                                                    int* __restrict__ tile_meta) {
  __shared__ int sid[ROWS];
  __shared__ int cnt[8];
  __shared__ int off[9];
  route_body(ids, sorted_flat, unsort, tile_meta, sid, cnt, off);
}

__global__ void zero_kernel(float4* __restrict__ p, int n4) {
  int i = blockIdx.x * blockDim.x + threadIdx.x;
  if (i < n4) p[i] = float4{0.f, 0.f, 0.f, 0.f};
}

// ------- kernel A: grid (64, 18) x 512 threads -------
// y<16: fp32 wi0/wi1 [E][1024][2048] -> bf16 [E][2048][1024], 256k x 128n
//   tiles (512B-contiguous reads; LDS [128 n][128 kpair] uints = 64KB with
//   row-quad XOR swizzle; uint4 drains 512B contiguous per 32-lane group).
// y==16: route (block x==0 only; LDS aliased onto t).
// y==17: zero the output buffer (fused-combine target), grid-stride.
__global__ __launch_bounds__(512, 4) void convT_wi(
    const float* __restrict__ wi0, const float* __restrict__ wi1,
    unsigned short* __restrict__ w0T, unsigned short* __restrict__ w1T,
    const int* __restrict__ ids, int* __restrict__ sorted_flat,
    int* __restrict__ unsort, int* __restrict__ tile_meta,
    float4* __restrict__ out4) {
  __shared__ unsigned t[128 * 128];  // [n][phys kpair], 64KB
  const int z = blockIdx.y;          // 0..17
  if (z == 16) {                     // ---- route ----
    if (blockIdx.x != 0) return;
    route_body(ids, sorted_flat, unsort, tile_meta,
               (int*)t, (int*)&t[4096], (int*)&t[4104]);
    return;
  }
  if (z == 17) {                     // ---- zero out (2048*1024 f32) ----
    const int n4 = (ROWS / 2) * D_DIM / 4;         // 524288 float4
    for (int i = blockIdx.x * 512 + threadIdx.x; i < n4; i += 64 * 512)
      out4[i] = float4{0.f, 0.f, 0.f, 0.f};
    return;
  }
  const int which = z >> 3, e = z & 7;
  const float* S = (which == 0 ? wi0 : wi1) + (size_t)e * D_DIM * F_DIM;
  unsigned short* Dp = (which == 0 ? w0T : w1T) + (size_t)e * D_DIM * F_DIM;
  const int n0 = (blockIdx.x & 15) * 128;   // F/128 = 16 n-tiles
  const int k0 = (blockIdx.x >> 4) * 256;   // D/256 = 4 k-tiles
  const int tid = threadIdx.x;
  const int nc  = tid & 31;    // float4 n-chunk (4 n each)
  const int kpb = tid >> 5;    // kpair base 0..15

  float4 v[8][2];
#pragma unroll
  for (int r = 0; r < 8; r++) {
    const int kp = kpb + r * 16;  // 0..127
    const float* p = S + (size_t)(k0 + 2 * kp) * F_DIM + n0 + nc * 4;
    v[r][0] = *(const float4*)p;
    v[r][1] = *(const float4*)(p + F_DIM);
  }
  __builtin_amdgcn_sched_barrier(0);  // keep packs from sinking above loads

#pragma unroll
  for (int r = 0; r < 8; r++) {
    const int kp = kpb + r * 16;
    const int q = kp >> 2, ql = kp & 3;
    const int col = ((q ^ (nc & 7)) << 2) | ql;  // phys uint within n-row
    t[(4 * nc + 0) * 128 + col] = pack_rn(v[r][0].x, v[r][1].x);
    t[(4 * nc + 1) * 128 + col] = pack_rn(v[r][0].y, v[r][1].y);
    t[(4 * nc + 2) * 128 + col] = pack_rn(v[r][0].z, v[r][1].z);
    t[(4 * nc + 3) * 128 + col] = pack_rn(v[r][0].w, v[r][1].w);
  }
  __syncthreads();

  const int c = tid & 31;  // kpair-quad 0..31 (16B chunk within 512B k-run)
#pragma unroll
  for (int s = 0; s < 8; s++) {
    const int n = (tid >> 5) + s * 16;
    const int col = (c ^ ((n >> 2) & 7)) << 2;
    const unsigned* qp = &t[n * 128 + col];
    uint4 o = make_uint4(qp[0], qp[1], qp[2], qp[3]);
    *(uint4*)(Dp + (size_t)(n0 + n) * D_DIM + k0 + c * 8) = o;
  }
}

// ---- wo convT rider body: 256 threads, 128(k) x 128(n) tile ----
// wo fp32 [E][2048 k][1024 n] -> woT bf16 [E][1024 n][2048 k].
// LDS t: [128 n][64 uint] = 32KB (aliased onto gemm1's SH).
__device__ __forceinline__ void convT_wo_body(const float* __restrict__ wo,
                                              unsigned short* __restrict__ woT,
                                              int id, unsigned* t) {
  const int e = id >> 7, rem = id & 127;     // 128 tiles/expert
  const int k0 = (rem >> 3) * 128;           // F/128 = 16 k-tiles
  const int n0 = (rem & 7) * 128;            // D/128 = 8 n-tiles
  const float* S = wo + (size_t)e * F_DIM * D_DIM;
  unsigned short* Dp = woT + (size_t)e * F_DIM * D_DIM;
  const int tid = threadIdx.x;
  const int nc = tid & 31, kpb = tid >> 5;   // kpb 0..7

  float4 v[8][2];
#pragma unroll
  for (int r = 0; r < 8; r++) {
    const int kp = kpb + r * 8;              // kpair 0..63
    const float* p = S + (size_t)(k0 + 2 * kp) * D_DIM + n0 + nc * 4;
    v[r][0] = *(const float4*)p;
    v[r][1] = *(const float4*)(p + D_DIM);
  }
  __builtin_amdgcn_sched_barrier(0);

#pragma unroll
  for (int r = 0; r < 8; r++) {
    const int kp = kpb + r * 8;
    const int ch = kp >> 2, ql = kp & 3;     // ch 0..15
    const int col = ((ch ^ (nc & 7)) << 2) | ql;   // 0..63
    t[(4 * nc + 0) * 64 + col] = pack_rn(v[r][0].x, v[r][1].x);
    t[(4 * nc + 1) * 64 + col] = pack_rn(v[r][0].y, v[r][1].y);
    t[(4 * nc + 2) * 64 + col] = pack_rn(v[r][0].z, v[r][1].z);
    t[(4 * nc + 3) * 64 + col] = pack_rn(v[r][0].w, v[r][1].w);
  }
  __syncthreads();

  const int c = tid & 15;                    // 16B chunk 0..15
#pragma unroll
  for (int s = 0; s < 8; s++) {
    const int n = (tid >> 4) + s * 16;       // 0..127
    const int col = (c ^ ((n >> 2) & 7)) << 2;
    const unsigned* qp = &t[n * 64 + col];
    uint4 o = make_uint4(qp[0], qp[1], qp[2], qp[3]);
    *(uint4*)(Dp + (size_t)(n0 + n) * F_DIM + k0 + c * 8) = o;
  }
}

// ---------------- gather: x fp32 -> x_sorted bf16 ----------------
__global__ __launch_bounds__(256) void gather_kernel(const float* __restrict__ x,
                                                     const int* __restrict__ sorted_flat,
                                                     unsigned short* __restrict__ xs) {
  const int r = blockIdx.x;
  const int tok = sorted_flat[r] >> 1;
  const float4 v = *(const float4*)(x + (size_t)tok * D_DIM + threadIdx.x * 4);
  *(uint2*)(xs + (size_t)r * D_DIM + threadIdx.x * 4) =
      make_uint2(pack_rn(v.x, v.y), pack_rn(v.z, v.w));
}

// swizzled frag address: physical chunk = logical_chunk ^ (row&7)
__device__ __forceinline__ int sw(int row, int chunk) {
  return row * 64 + ((chunk ^ (row & 7)) << 3);
}

// ------- GEMM1 (+wo-convT riders): grid (72, 32) x 256 threads -------
// x<40: xs @ (w0T,w1T) -> h = silu(g0)*g1, 128(m) x 64(n) tiles.
// x>=40: rider id (x-40) + 32*y in [0,1024): wo convT tile (LDS aliased).
__global__ __launch_bounds__(256, 3) void gemm1_kernel(
    const unsigned short* __restrict__ xs, const unsigned short* __restrict__ w0T,
    const unsigned short* __restrict__ w1T, const int* __restrict__ tile_meta,
    unsigned short* __restrict__ h, const float* __restrict__ wo,
    unsigned short* __restrict__ woT) {
  __shared__ unsigned short SH[16384];   // 32KB: As | B0s | B1s, or rider tile
  if (blockIdx.x >= MAXTILE) {
    convT_wo_body(wo, woT, (int)(blockIdx.x - MAXTILE) + 32 * (int)blockIdx.y,
                  (unsigned*)SH);
    return;
  }
  unsigned short* As  = SH;              // 128x64
  unsigned short* B0s = SH + 8192;       // 64x64
  unsigned short* B1s = SH + 12288;      // 64x64
  const int tile = blockIdx.x;
  if (tile >= tile_meta[0]) return;
  const int row0 = tile_meta[1 + 3 * tile];
  const int rowEnd = tile_meta[2 + 3 * tile];
  const int e = tile_meta[3 + 3 * tile];
  const int n0 = blockIdx.y * 64;
  const unsigned short* W0 = w0T + ((size_t)e * F_DIM + n0) * D_DIM;
  const unsigned short* W1 = w1T + ((size_t)e * F_DIM + n0) * D_DIM;

  const int tid = threadIdx.x;
  const int lane = tid & 63, wv = tid >> 6;
  const int wm = (wv & 1) * 64, wn = (wv >> 1) * 32;
  const int lm = lane & 15, lq = lane >> 4;
  const int srow = lane >> 3;                       // staging row-in-chunk
  const int skk = ((lane & 7) ^ srow) << 3;         // swizzled source elem off

  f32x4 acc0[4][2], acc1[4][2];
#pragma unroll
  for (int i = 0; i < 4; i++)
#pragma unroll
    for (int j = 0; j < 2; j++) { acc0[i][j] = 0.f; acc1[i][j] = 0.f; }

  for (int k0 = 0; k0 < D_DIM; k0 += 64) {
    __syncthreads();
#pragma unroll
    for (int r = 0; r < 4; r++) {                 // A: 16 chunks, 4/wave
      const int c = r * 4 + wv;
      const int m = c * 8 + srow;
      int mc = row0 + m; if (mc > ROWS - 1) mc = ROWS - 1;
      load16(xs + (size_t)mc * D_DIM + k0 + skk, (char*)As + c * 1024);
    }
#pragma unroll
    for (int r = 0; r < 2; r++) {                 // B0,B1: 8 chunks, 2/wave
      const int c = r * 4 + wv;
      const int m = c * 8 + srow;
      load16(W0 + (size_t)m * D_DIM + k0 + skk, (char*)B0s + c * 1024);
      load16(W1 + (size_t)m * D_DIM + k0 + skk, (char*)B1s + c * 1024);
    }
    __syncthreads();
#pragma unroll
    for (int ks = 0; ks < 64; ks += 32) {
      const int cb = (ks >> 3) + lq;
      s16x8 af[4], b0[2], b1[2];
#pragma unroll
      for (int t = 0; t < 4; t++)
        af[t] = *(const s16x8*)&As[sw(wm + t * 16 + lm, cb)];
#pragma unroll
      for (int t = 0; t < 2; t++) {
        b0[t] = *(const s16x8*)&B0s[sw(wn + t * 16 + lm, cb)];
        b1[t] = *(const s16x8*)&B1s[sw(wn + t * 16 + lm, cb)];
      }
#pragma unroll
      for (int im = 0; im < 4; im++)
#pragma unroll
        for (int in = 0; in < 2; in++) {
          acc0[im][in] = __builtin_amdgcn_mfma_f32_16x16x32_bf16(
              af[im], b0[in], acc0[im][in], 0, 0, 0);
          acc1[im][in] = __builtin_amdgcn_mfma_f32_16x16x32_bf16(
              af[im], b1[in], acc1[im][in], 0, 0, 0);
        }
    }
  }
#pragma unroll
  for (int im = 0; im < 4; im++) {
    int gmB = row0 + wm + im * 16 + lq * 4;
#pragma unroll
    for (int in = 0; in < 2; in++) {
      int gn = n0 + wn + in * 16 + lm;
#pragma unroll
      for (int r = 0; r < 4; r++) {
        int gm = gmB + r;
        if (gm < rowEnd) {
          float g = acc0[im][in][r];
          float s = g / (1.f + __expf(-g));
          h[(size_t)gm * F_DIM + gn] = bf_rn(s * acc1[im][in][r]);
        }
      }
    }
  }
}

// --- GEMM2 (+fused combine): h @ woT, atomicAdd tw*acc into out[tok] ---
__global__ __launch_bounds__(256, 4) void gemm2_kernel(
    const unsigned short* __restrict__ h, const unsigned short* __restrict__ woT,
    const float* __restrict__ tw, const int* __restrict__ sorted_flat,
    const int* __restrict__ tile_meta, float* __restrict__ out) {
  __shared__ unsigned short As[128 * 64];
  __shared__ unsigned short Bs[64 * 64];
  __shared__ int sTok[128];
  __shared__ float sWgt[128];
  const int tile = blockIdx.x;
  if (tile >= tile_meta[0]) return;
  const int row0 = tile_meta[1 + 3 * tile];
  const int rowEnd = tile_meta[2 + 3 * tile];
  const int e = tile_meta[3 + 3 * tile];
  const int n0 = blockIdx.y * 64;
  const unsigned short* W = woT + ((size_t)e * D_DIM + n0) * F_DIM;

  const int tid = threadIdx.x;
  if (tid < 128) {
    int r = row0 + tid; if (r > ROWS - 1) r = ROWS - 1;
    int fl = sorted_flat[r];
    sTok[tid] = fl >> 1;
    sWgt[tid] = tw[fl];
  }
  const int lane = tid & 63, wv = tid >> 6;
  const int wm = (wv & 1) * 64, wn = (wv >> 1) * 32;
  const int lm = lane & 15, lq = lane >> 4;
  const int srow = lane >> 3;
  const int skk = ((lane & 7) ^ srow) << 3;

  f32x4 acc[4][2];
#pragma unroll
  for (int i = 0; i < 4; i++)
#pragma unroll
    for (int j = 0; j < 2; j++) acc[i][j] = 0.f;

  for (int k0 = 0; k0 < F_DIM; k0 += 64) {
    __syncthreads();
#pragma unroll
    for (int r = 0; r < 4; r++) {
      const int c = r * 4 + wv;
      const int m = c * 8 + srow;
      int mc = row0 + m; if (mc > ROWS - 1) mc = ROWS - 1;
      load16(h + (size_t)mc * F_DIM + k0 + skk, (char*)As + c * 1024);
    }
#pragma unroll
    for (int r = 0; r < 2; r++) {
      const int c = r * 4 + wv;
      const int m = c * 8 + srow;
      load16(W + (size_t)m * F_DIM + k0 + skk, (char*)Bs + c * 1024);
    }
    __syncthreads();
#pragma unroll
    for (int ks = 0; ks < 64; ks += 32) {
      const int cb = (ks >> 3) + lq;
      s16x8 af[4], bf[2];
#pragma unroll
      for (int t = 0; t < 4; t++)
        af[t] = *(const s16x8*)&As[sw(wm + t * 16 + lm, cb)];
#pragma unroll
      for (int t = 0; t < 2; t++)
        bf[t] = *(const s16x8*)&Bs[sw(wn + t * 16 + lm, cb)];
#pragma unroll
      for (int im = 0; im < 4; im++)
#pragma unroll
        for (int in = 0; in < 2; in++)
          acc[im][in] = __builtin_amdgcn_mfma_f32_16x16x32_bf16(
              af[im], bf[in], acc[im][in], 0, 0, 0);
    }
  }
#pragma unroll
  for (int im = 0; im < 4; im++) {
    int lrB = wm + im * 16 + lq * 4;
#pragma unroll
    for (int in = 0; in < 2; in++) {
      int gn = n0 + wn + in * 16 + lm;
#pragma unroll
      for (int r = 0; r < 4; r++) {
        int lr = lrB + r;
        int gm = row0 + lr;
        if (gm < rowEnd)
          atomicAdd(out + (size_t)sTok[lr] * D_DIM + gn,
                    sWgt[lr] * acc[im][in][r]);
      }
    }
  }
}

// ================= fallback (round-0) kernels, small-ws path =================
__device__ __forceinline__ void stage_bt(const float* __restrict__ Wt, int ldw,
                                         unsigned short* Bs, int tid) {
#pragma unroll
  for (int it = 0; it < 4; it++) {
    const int kp = (tid & 7) + it * 8;
    const int nq = tid >> 3;
    const float* p = Wt + (size_t)(2 * kp) * ldw + nq * 4;
    const float4 va = *(const float4*)p;
    const float4 vb = *(const float4*)(p + ldw);
    unsigned short* b = Bs + (nq * 4) * LDK + 2 * kp;
    *(unsigned*)(b)           = pack_trunc(va.x, vb.x);
    *(unsigned*)(b + LDK)     = pack_trunc(va.y, vb.y);
    *(unsigned*)(b + 2 * LDK) = pack_trunc(va.z, vb.z);
    *(unsigned*)(b + 3 * LDK) = pack_trunc(va.w, vb.w);
  }
}

__global__ __launch_bounds__(256, 2) void gemm1_fb(
    const float* __restrict__ x, const float* __restrict__ wi0,
    const float* __restrict__ wi1, const int* __restrict__ sorted_flat,
    const int* __restrict__ tile_meta, unsigned short* __restrict__ h) {
  __shared__ unsigned short As[128 * LDK];
  __shared__ unsigned short B0s[128 * LDK];
  __shared__ unsigned short B1s[128 * LDK];
  __shared__ int tok[128];
  const int tile = blockIdx.x;
  if (tile >= tile_meta[0]) return;
  const int row0 = tile_meta[1 + 3 * tile];
  const int rowEnd = tile_meta[2 + 3 * tile];
  const int e = tile_meta[3 + 3 * tile];
  const int n0 = blockIdx.y * 128;
  const float* W0 = wi0 + (size_t)e * D_DIM * F_DIM;
  const float* W1 = wi1 + (size_t)e * D_DIM * F_DIM;
  const int tid = threadIdx.x;
  if (tid < 128) {
    int r = row0 + tid; if (r > ROWS - 1) r = ROWS - 1;
    tok[tid] = sorted_flat[r] >> 1;
  }
  f32x4 acc0[4][4], acc1[4][4];
#pragma unroll
  for (int i = 0; i < 4; i++)
#pragma unroll
    for (int j = 0; j < 4; j++) { acc0[i][j] = 0.f; acc1[i][j] = 0.f; }
  const int lane = tid & 63, wv = tid >> 6;
  const int wm = (wv & 1) * 64, wn = (wv >> 1) * 64;
  const int lm = lane & 15, lq = lane >> 4;
  for (int k0 = 0; k0 < D_DIM; k0 += 64) {
    __syncthreads();
#pragma unroll
    for (int i = 0; i < 8; i++) {
      int idx = tid + i * 256;
      int m = idx >> 4, kq = idx & 15;
      float4 v = *(const float4*)(x + (size_t)tok[m] * D_DIM + k0 + kq * 4);
      *(uint2*)&As[m * LDK + kq * 4] =
          make_uint2(pack_trunc(v.x, v.y), pack_trunc(v.z, v.w));
    }
    stage_bt(W0 + (size_t)k0 * F_DIM + n0, F_DIM, B0s, tid);
    stage_bt(W1 + (size_t)k0 * F_DIM + n0, F_DIM, B1s, tid);
    __syncthreads();
#pragma unroll
    for (int ks = 0; ks < 64; ks += 32) {
      s16x8 af[4], b0[4], b1[4];
#pragma unroll
      for (int t = 0; t < 4; t++) {
        af[t] = *(const s16x8*)&As[(wm + t * 16 + lm) * LDK + ks + lq * 8];
        b0[t] = *(const s16x8*)&B0s[(wn + t * 16 + lm) * LDK + ks + lq * 8];
        b1[t] = *(const s16x8*)&B1s[(wn + t * 16 + lm) * LDK + ks + lq * 8];
      }
#pragma unroll
      for (int im = 0; im < 4; im++)
#pragma unroll
        for (int in = 0; in < 4; in++) {
          acc0[im][in] = __builtin_amdgcn_mfma_f32_16x16x32_bf16(
              af[im], b0[in], acc0[im][in], 0, 0, 0);
          acc1[im][in] = __builtin_amdgcn_mfma_f32_16x16x32_bf16(
              af[im], b1[in], acc1[im][in], 0, 0, 0);
        }
    }
  }
#pragma unroll
  for (int im = 0; im < 4; im++) {
    int gmB = row0 + wm + im * 16 + lq * 4;
#pragma unroll
    for (int in = 0; in < 4; in++) {
      int gn = n0 + wn + in * 16 + lm;
#pragma unroll
      for (int r = 0; r < 4; r++) {
        int gm = gmB + r;
        if (gm < rowEnd) {
          float g = acc0[im][in][r];
          float s = g / (1.f + __expf(-g));
          h[(size_t)gm * F_DIM + gn] = bf_rn(s * acc1[im][in][r]);
        }
      }
    }
  }
}

__global__ __launch_bounds__(256, 3) void gemm2_fb(
    const unsigned short* __restrict__ h, const float* __restrict__ wo,
    const float* __restrict__ tw, const int* __restrict__ sorted_flat,
    const int* __restrict__ tile_meta, float* __restrict__ out) {
  __shared__ unsigned short As[128 * LDK];
  __shared__ unsigned short Bs[128 * LDK];
  __shared__ int sTok[128];
  __shared__ float sWgt[128];
  const int tile = blockIdx.x;
  if (tile >= tile_meta[0]) return;
  const int row0 = tile_meta[1 + 3 * tile];
  const int rowEnd = tile_meta[2 + 3 * tile];
  const int e = tile_meta[3 + 3 * tile];
  const int n0 = blockIdx.y * 128;
  const float* W = wo + (size_t)e * F_DIM * D_DIM;
  const int tid = threadIdx.x;
  if (tid < 128) {
    int r = row0 + tid; if (r > ROWS - 1) r = ROWS - 1;
    int fl = sorted_flat[r];
    sTok[tid] = fl >> 1;
    sWgt[tid] = tw[fl];
  }
  f32x4 acc[4][4];
#pragma unroll
  for (int i = 0; i < 4; i++)
#pragma unroll
    for (int j = 0; j < 4; j++) acc[i][j] = 0.f;
  const int lane = tid & 63, wv = tid >> 6;
  const int wm = (wv & 1) * 64, wn = (wv >> 1) * 64;
  const int lm = lane & 15, lq = lane >> 4;
  for (int k0 = 0; k0 < F_DIM; k0 += 64) {
    __syncthreads();
#pragma unroll
    for (int i = 0; i < 8; i++) {
      int idx = tid + i * 256;
      int m = idx >> 4, kq = idx & 15;
      int gm = row0 + m; if (gm > ROWS - 1) gm = ROWS - 1;
      *(uint2*)&As[m * LDK + kq * 4] =
          *(const uint2*)(h + (size_t)gm * F_DIM + k0 + kq * 4);
    }
    stage_bt(W + (size_t)k0 * D_DIM + n0, D_DIM, Bs, tid);
    __syncthreads();
#pragma unroll
    for (int ks = 0; ks < 64; ks += 32) {
      s16x8 af[4], bf[4];
#pragma unroll
      for (int t = 0; t < 4; t++) {
        af[t] = *(const s16x8*)&As[(wm + t * 16 + lm) * LDK + ks + lq * 8];
        bf[t] = *(const s16x8*)&Bs[(wn + t * 16 + lm) * LDK + ks + lq * 8];
      }
#pragma unroll
      for (int im = 0; im < 4; im++)
#pragma unroll
        for (int in = 0; in < 4; in++)
          acc[im][in] = __builtin_amdgcn_mfma_f32_16x16x32_bf16(
              af[im], bf[in], acc[im][in], 0, 0, 0);
    }
  }
#pragma unroll
  for (int im = 0; im < 4; im++) {
    int lrB = wm + im * 16 + lq * 4;
#pragma unroll
    for (int in = 0; in < 4; in++) {
      int gn = n0 + wn + in * 16 + lm;
#pragma unroll
      for (int r = 0; r < 4; r++) {
        int lr = lrB + r;
        int gm = row0 + lr;
        if (gm < rowEnd)
          atomicAdd(out + (size_t)sTok[lr] * D_DIM + gn, sWgt[lr] * acc[im][in][r]);
      }
    }
  }
}

extern "C" void kernel_launch(void* const* d_in, const int* in_sizes, int n_in,
                              void* d_out, int out_size, void* d_ws, size_t ws_size,
                              hipStream_t stream) {
  const float* x   = (const float*)d_in[0];
  const float* tw  = (const float*)d_in[1];
  const int*   ids = (const int*)d_in[2];
  const float* wi0 = (const float*)d_in[3];
  const float* wi1 = (const float*)d_in[4];
  const float* wo  = (const float*)d_in[5];
  float* out = (float*)d_out;

  int* tile_meta = (int*)d_ws;            // 256 ints
  int* sorted_flat = tile_meta + 256;     // 4096 ints
  int* unsort = sorted_flat + ROWS;       // 4096 ints (ends < 64KB)

  const size_t MB = 1024 * 1024;
  const size_t XS_OFF = 64 * 1024;
  const size_t H_OFF  = XS_OFF + 8 * MB;
  const size_t W0_OFF = H_OFF + 16 * MB;
  const size_t W1_OFF = W0_OFF + 32 * MB;
  const size_t WO_OFF = W1_OFF + 32 * MB;
  const size_t NEED   = WO_OFF + 32 * MB;  // ~120.06 MB

  if (ws_size >= NEED) {
    unsigned short* xs  = (unsigned short*)((char*)d_ws + XS_OFF);
    unsigned short* h   = (unsigned short*)((char*)d_ws + H_OFF);
    unsigned short* w0T = (unsigned short*)((char*)d_ws + W0_OFF);
    unsigned short* w1T = (unsigned short*)((char*)d_ws + W1_OFF);
    unsigned short* woT = (unsigned short*)((char*)d_ws + WO_OFF);

    // A: wi0/wi1 convT + route (y=16) + out-zero (y=17)
    convT_wi<<<dim3(64, 18), 512, 0, stream>>>(wi0, wi1, w0T, w1T,
                                               ids, sorted_flat, unsort,
                                               tile_meta, (float4*)out);
    gather_kernel<<<ROWS, 256, 0, stream>>>(x, sorted_flat, xs);
    // B: gemm1 tiles (x<40) + wo convT riders (x>=40, 1024 blocks)
    gemm1_kernel<<<dim3(MAXTILE + 32, F_DIM / 64), 256, 0, stream>>>(
        xs, w0T, w1T, tile_meta, h, wo, woT);
    // C: gemm2 + fused combine
    gemm2_kernel<<<dim3(MAXTILE, D_DIM / 64), 256, 0, stream>>>(h, woT, tw,
                                                                sorted_flat,
                                                                tile_meta, out);
  } else {
    unsigned short* hfb = (unsigned short*)((char*)d_ws + XS_OFF);
    route_kernel<<<1, 512, 0, stream>>>(ids, sorted_flat, unsort, tile_meta);
    zero_kernel<<<(ROWS / 2 * D_DIM / 4 + 255) / 256, 256, 0, stream>>>(
        (float4*)out, ROWS / 2 * D_DIM / 4);
    gemm1_fb<<<dim3(MAXTILE, F_DIM / 128), 256, 0, stream>>>(x, wi0, wi1,
                                                             sorted_flat,
                                                             tile_meta, hfb);
    gemm2_fb<<<dim3(MAXTILE, D_DIM / 128), 256, 0, stream>>>(hfb, wo, tw,
                                                             sorted_flat,
                                                             tile_meta, out);
  }
}